// Round 8
// baseline (75.404 us; speedup 1.0000x reference)
//
#include <hip/hip_runtime.h>

#define NROWS 65536
#define DIM   64
#define NE    512

// d_out is FLOAT32: [ z_q (4194304) | indices-as-float (65536) | loss (1) ]
// Scratch (inside z_q region, fully overwritten later by vq_write):
//   bytes [0,131072)       : preSplit  — 512 rows x 256B: 8x16B (-2e)_hi chunks
//                            XOR-swizzled in [0,128), (-2e)_lo mirrored at +128
//   bytes [131072,139264)  : preY      — 512 x 16B: (ynorm_hi, ynorm_lo, 0...)
//   floats [34816,35328)   : ynorm f32 (np-pairwise, exact)
//   floats [1048576,...)   : cand u32 per row: ca | cb<<9 | flag<<18
#define PREY_BYTES 131072
#define YN_FLT     34816
#define CAND_FLT   1048576

typedef __attribute__((ext_vector_type(8)))  short bf16x8;
typedef __attribute__((ext_vector_type(16))) float f32x16;

static __device__ __forceinline__ unsigned short bf16rne(float x) {
    unsigned int u = __float_as_uint(x);
    u += 0x7FFFu + ((u >> 16) & 1u);            // RNE (finite inputs only)
    return (unsigned short)(u >> 16);
}
static __device__ __forceinline__ float bf16tof(unsigned short h) {
    return __uint_as_float(((unsigned int)h) << 16);
}

// K0: one-time codebook prep (512 rows, 2 blocks).
__global__ __launch_bounds__(256) void vq_prep(
    const float* __restrict__ ew, float* out)
{
    const int r = blockIdx.x * 256 + threadIdx.x;     // 0..511
    float a[64];
    const float4* src = (const float4*)(ew + (size_t)r * DIM);
    #pragma unroll
    for (int q = 0; q < 16; ++q) {
        float4 v = src[q];
        a[q*4+0]=v.x; a[q*4+1]=v.y; a[q*4+2]=v.z; a[q*4+3]=v.w;
    }
    // numpy-pairwise ||e||^2 (exact np f32 order)
    float rc[8];
    #pragma unroll
    for (int j = 0; j < 8; ++j) rc[j] = __fmul_rn(a[j], a[j]);
    #pragma unroll
    for (int i = 8; i < 64; i += 8)
        #pragma unroll
        for (int j = 0; j < 8; ++j)
            rc[j] = __fadd_rn(rc[j], __fmul_rn(a[i+j], a[i+j]));
    float Y = __fadd_rn(__fadd_rn(__fadd_rn(rc[0],rc[1]),__fadd_rn(rc[2],rc[3])),
                        __fadd_rn(__fadd_rn(rc[4],rc[5]),__fadd_rn(rc[6],rc[7])));
    out[YN_FLT + r] = Y;
    // ynorm split-bf16 fragment (k-lanes 0,1 of the extra MFMA chunk)
    unsigned short ynh = bf16rne(Y);
    unsigned short ynl = bf16rne(Y - bf16tof(ynh));
    bf16x8 py = {};
    py[0] = (short)ynh; py[1] = (short)ynl;
    *(bf16x8*)((char*)out + PREY_BYTES + r*16) = py;
    // -2e split-bf16, swizzle baked
    const int sw = (r & 7) << 4;
    char* base = (char*)out + (size_t)r * 256;
    #pragma unroll
    for (int c = 0; c < 8; ++c) {
        bf16x8 h, l;
        #pragma unroll
        for (int j = 0; j < 8; ++j) {
            float x = -2.0f * a[c*8+j];
            unsigned short hb = bf16rne(x);
            h[j] = (short)hb;
            l[j] = (short)bf16rne(x - bf16tof(hb));
        }
        int off = (c*16) ^ sw;
        *(bf16x8*)(base + off) = h;
        *(bf16x8*)(base + off + 128) = l;
    }
}

// K1: MFMA ranking. 512 blocks x 4 waves x 32 rows. Half-codebook LDS dbuf-free
// staging (2 halves), ynorm baked into accumulator via 5th MFMA chunk.
// Emits one u32 per row: top-1 of each half-lane pool + near-tie flag.
__global__ __launch_bounds__(256) void vq_mfma(
    const float* __restrict__ z, const float* pre, unsigned int* cand)
{
    __shared__ __align__(16) char lds[65536 + 8192];  // half preSplit + preY
    const int tid  = threadIdx.x;
    const int lane = tid & 63;
    const int w    = tid >> 6;
    const int hh   = lane >> 5;
    const int l31  = lane & 31;
    const int zrow = blockIdx.x * 128 + w * 32 + l31;

    // ---- this lane's z fragments (split-bf16), B layout: n=lane&31, k=8*hh+j ----
    bf16x8 zh[4], zl[4];
    {
        const float* zp = z + (size_t)zrow * DIM + hh * 8;
        #pragma unroll
        for (int kt = 0; kt < 4; ++kt) {
            float4 p0 = *(const float4*)(zp + kt*16);
            float4 p1 = *(const float4*)(zp + kt*16 + 4);
            float a[8] = {p0.x,p0.y,p0.z,p0.w,p1.x,p1.y,p1.z,p1.w};
            bf16x8 hv, lv;
            #pragma unroll
            for (int j = 0; j < 8; ++j) {
                unsigned short hb = bf16rne(a[j]);
                hv[j] = (short)hb;
                lv[j] = (short)bf16rne(a[j] - bf16tof(hb));
            }
            zh[kt] = hv; zl[kt] = lv;
        }
    }

    // ---- stage preY (8KB, once) ----
    #pragma unroll
    for (int i = 0; i < 2; ++i)
        *(float4*)(lds + 65536 + (tid + 256*i)*16) =
            *(const float4*)((const char*)pre + PREY_BYTES + (tid + 256*i)*16);

    const bf16x8 zero8 = {};
    bf16x8 bones = {};
    if (hh == 0) { bones[0] = (short)0x3F80; bones[1] = (short)0x3F80; }  // 1.0bf16

    float d1 = 3.4e38f, d2 = 3.4e38f;
    int   i1 = 0;

    for (int h = 0; h < 2; ++h) {
        __syncthreads();           // prior half's readers done (covers preY at h=0)
        #pragma unroll
        for (int i = 0; i < 16; ++i)
            *(float4*)(lds + tid*16 + i*4096) =
                *(const float4*)((const char*)pre + h*65536 + tid*16 + i*4096);
        __syncthreads();

        for (int t = 0; t < 8; ++t) {
            const int   arow  = t*32 + l31;       // lds-local row (== global mod 8)
            const char* abase = lds + arow*256;
            const int   sw    = (arow & 7) << 4;
            f32x16 acc;
            #pragma unroll
            for (int g = 0; g < 16; ++g) acc[g] = 0.f;
            #pragma unroll
            for (int kt = 0; kt < 4; ++kt) {
                const int kb = (kt*32 + hh*16) ^ sw;
                bf16x8 ah = *(const bf16x8*)(abase + kb);
                bf16x8 al = *(const bf16x8*)(abase + kb + 128);
                acc = __builtin_amdgcn_mfma_f32_32x32x16_bf16(ah, zh[kt], acc, 0,0,0);
                acc = __builtin_amdgcn_mfma_f32_32x32x16_bf16(ah, zl[kt], acc, 0,0,0);
                acc = __builtin_amdgcn_mfma_f32_32x32x16_bf16(al, zh[kt], acc, 0,0,0);
            }
            // + ynorm via extra chunk: A=(ynh,ynl,0..), B=(1,1,0..)
            bf16x8 ay = *(const bf16x8*)(lds + 65536 + (h*256 + t*32 + l31)*16);
            if (hh) ay = zero8;
            acc = __builtin_amdgcn_mfma_f32_32x32x16_bf16(ay, bones, acc, 0,0,0);

            const int ebase = h*256 + t*32 + 4*hh;
            #pragma unroll
            for (int g = 0; g < 16; ++g) {
                float d = acc[g];                  // = ynorm[e] - 2*z.e (approx)
                int   e = ebase + (g & 3) + 8*(g >> 2);
                d2 = fminf(fmaxf(d, d1), d2);
                bool bt = d < d1;
                i1 = bt ? e : i1;
                d1 = fminf(d, d1);
            }
        }
    }

    // ---- merge half-lane pools, emit packed candidates + near-tie flag ----
    float od1 = __shfl_xor(d1, 32, 64);
    int   oi1 = __shfl_xor(i1, 32, 64);
    float od2 = __shfl_xor(d2, 32, 64);
    float s1 = fminf(d1, od1);
    float s2 = fminf(fmaxf(d1, od1), fminf(d2, od2));   // <= true union 2nd-best
    bool flag = s2 < s1 + 4e-5f;
    if (hh == 0) {
        unsigned int pk = ((unsigned)i1 & 511u) | (((unsigned)oi1 & 511u) << 9)
                        | (flag ? (1u << 18) : 0u);
        cand[zrow] = pk;
    }
}

// K2: np-f32 rerank of the 2 candidates (f64 dots), wave-parallel exact np
// rescan for flagged rows, loss partials, index write. (round-7 proven logic)
__global__ __launch_bounds__(256) void vq_rerank(
    const float* __restrict__ z, const float* __restrict__ ew,
    const float* scratch, float* out, float* __restrict__ part)
{
    __shared__ float yn[NE];
    __shared__ float wsum[4];
    const int tid  = threadIdx.x;
    const int lane = tid & 63;
    const int w    = tid >> 6;
    const int R0   = blockIdx.x * 256;

    #pragma unroll
    for (int i = 0; i < 2; ++i) yn[tid + 256*i] = scratch[YN_FLT + tid + 256*i];
    __syncthreads();

    const unsigned int* candp = (const unsigned int*)(scratch + CAND_FLT);
    unsigned int pk = candp[R0 + tid];
    int  ca   = pk & 511, cb = (pk >> 9) & 511;
    bool flag = (pk >> 18) & 1u;

    float zr[64];
    {
        const float4* zsrc = (const float4*)(z + (size_t)(R0 + tid) * DIM);
        #pragma unroll
        for (int q = 0; q < 16; ++q) {
            float4 v = zsrc[q];
            zr[q*4+0]=v.x; zr[q*4+1]=v.y; zr[q*4+2]=v.z; zr[q*4+3]=v.w;
        }
    }
    // np-pairwise ||z||^2
    float rc[8];
    #pragma unroll
    for (int j = 0; j < 8; ++j) rc[j] = __fmul_rn(zr[j], zr[j]);
    #pragma unroll
    for (int i = 8; i < 64; i += 8)
        #pragma unroll
        for (int j = 0; j < 8; ++j)
            rc[j] = __fadd_rn(rc[j], __fmul_rn(zr[i+j], zr[i+j]));
    float xn = __fadd_rn(__fadd_rn(__fadd_rn(rc[0],rc[1]),__fadd_rn(rc[2],rc[3])),
                         __fadd_rn(__fadd_rn(rc[4],rc[5]),__fadd_rn(rc[6],rc[7])));

    // np-f32 rerank: d = fl32(fl32(X+Y) - 2*fl64dot)
    float bestd = 3.4e38f; int win = -1;
    #pragma unroll
    for (int c = 0; c < 2; ++c) {
        int ic = (c == 0) ? ca : cb;
        const float* ep = ew + (size_t)ic * DIM;
        double m = 0.0;
        #pragma unroll
        for (int q = 0; q < 16; ++q) {
            float4 ev = *(const float4*)(ep + q*4);
            m = fma((double)zr[q*4+0], (double)ev.x, m);
            m = fma((double)zr[q*4+1], (double)ev.y, m);
            m = fma((double)zr[q*4+2], (double)ev.z, m);
            m = fma((double)zr[q*4+3], (double)ev.w, m);
        }
        float W = __fadd_rn(xn, yn[ic]);
        float d = __fadd_rn(W, -(2.0f * (float)m));
        if (win < 0 || d < bestd || (d == bestd && ic < win)) { bestd = d; win = ic; }
    }

    // flagged rows: wave-parallel exact np rescan over all 512 embeds
    unsigned long long mb = __ballot(flag);
    while (mb) {
        int fl = __ffsll(mb) - 1;
        mb &= mb - 1;
        float xnf = __shfl(xn, fl, 64);
        const float* zq = z + (size_t)(R0 + w*64 + fl) * DIM;
        float bd = 3.4e38f; int bi = NE;
        for (int k = 0; k < 8; ++k) {
            int e = lane + 64*k;
            const float* ep = ew + (size_t)e * DIM;
            double m = 0.0;
            #pragma unroll
            for (int q = 0; q < 16; ++q) {
                float4 ev = *(const float4*)(ep + q*4);
                float4 zv = *(const float4*)(zq + q*4);
                m = fma((double)zv.x, (double)ev.x, m);
                m = fma((double)zv.y, (double)ev.y, m);
                m = fma((double)zv.z, (double)ev.z, m);
                m = fma((double)zv.w, (double)ev.w, m);
            }
            float W = __fadd_rn(xnf, yn[e]);
            float d = __fadd_rn(W, -(2.0f * (float)m));
            if (d < bd || (d == bd && e < bi)) { bd = d; bi = e; }
        }
        #pragma unroll
        for (int off = 32; off >= 1; off >>= 1) {
            float od = __shfl_xor(bd, off, 64);
            int   oi = __shfl_xor(bi, off, 64);
            if (od < bd || (od == bd && oi < bi)) { bd = od; bi = oi; }
        }
        if (lane == fl) win = bi;
    }

    // exact f64 ||z - e_win||^2 for loss; write f32 index
    const float* ewn = ew + (size_t)win * DIM;
    double dd = 0.0;
    #pragma unroll
    for (int q = 0; q < 16; ++q) {
        float4 ev = *(const float4*)(ewn + q*4);
        double x0 = (double)zr[q*4+0] - (double)ev.x;
        double x1 = (double)zr[q*4+1] - (double)ev.y;
        double x2 = (double)zr[q*4+2] - (double)ev.z;
        double x3 = (double)zr[q*4+3] - (double)ev.w;
        dd = fma(x0,x0,dd); dd = fma(x1,x1,dd);
        dd = fma(x2,x2,dd); dd = fma(x3,x3,dd);
    }
    out[(size_t)NROWS*DIM + R0 + tid] = (float)win;

    float s = (float)dd;
    #pragma unroll
    for (int off = 32; off >= 1; off >>= 1) s += __shfl_xor(s, off, 64);
    if (lane == 0) wsum[w] = s;
    __syncthreads();
    if (tid == 0) part[blockIdx.x] = wsum[0]+wsum[1]+wsum[2]+wsum[3];
}

// K3: gather ew by final indices, write full z_q chunk (overwrites scratch).
__global__ __launch_bounds__(256) void vq_write(
    const float* __restrict__ ew, float* out)
{
    __shared__ int ridx[64];
    const int tid = threadIdx.x;
    const int R0  = blockIdx.x * 64;
    if (tid < 64)
        ridx[tid] = ((int)out[(size_t)NROWS * DIM + R0 + tid]) & (NE - 1);
    __syncthreads();
    #pragma unroll
    for (int i = 0; i < 4; ++i) {
        int f4  = tid + 256 * i;
        int row = f4 >> 4;
        int c4  = f4 & 15;
        float4 v = *(const float4*)(ew + (size_t)ridx[row] * DIM + c4 * 4);
        *(float4*)(out + (size_t)R0 * DIM + (size_t)f4 * 4) = v;
    }
}

// K4: f64 sum of 256 per-block partials -> loss slot.
__global__ __launch_bounds__(256) void vq_loss(
    const float* __restrict__ part, float* out)
{
    __shared__ double ws[4];
    int tid = threadIdx.x;
    double s = (double)part[tid];
    #pragma unroll
    for (int off = 32; off >= 1; off >>= 1) s += __shfl_xor(s, off, 64);
    if ((tid & 63) == 0) ws[tid >> 6] = s;
    __syncthreads();
    if (tid == 0)
        out[(size_t)NROWS*DIM + NROWS] =
            (float)(0.25 * (ws[0]+ws[1]+ws[2]+ws[3]) / (double)((size_t)NROWS*DIM));
}

extern "C" void kernel_launch(void* const* d_in, const int* in_sizes, int n_in,
                              void* d_out, int out_size, void* d_ws, size_t ws_size,
                              hipStream_t stream) {
    const float* z  = (const float*)d_in[0];
    const float* ew = (const float*)d_in[1];
    float* out  = (float*)d_out;
    float* part = (float*)d_ws;   // 256 floats, fully overwritten every call
    vq_prep  <<<2,    256, 0, stream>>>(ew, out);
    vq_mfma  <<<512,  256, 0, stream>>>(z, out, (unsigned int*)(out + CAND_FLT));
    vq_rerank<<<256,  256, 0, stream>>>(z, ew, out, out, part);
    vq_write <<<1024, 256, 0, stream>>>(ew, out);
    vq_loss  <<<1,    256, 0, stream>>>(part, out);
}